// Round 13
// baseline (3206.128 us; speedup 1.0000x reference)
//
#include <hip/hip_runtime.h>
#include <math.h>
#include <stdint.h>

#define THR  0.05f
#define BETA 0.9181805491303656f
#define B_SZ 64
#define T_STEPS 25

using h8    = __attribute__((ext_vector_type(8))) _Float16;
using f32x4 = __attribute__((ext_vector_type(4))) float;

__device__ __forceinline__ float sigf(float x) { return 1.0f / (1.0f + __expf(-x)); }
__device__ __forceinline__ float tanh_fast(float x) {
    const float xc = fminf(fmaxf(x, -10.0f), 10.0f);
    const float e = __expf(2.0f * xc);
    return (e - 1.0f) / (e + 1.0f);
}

// ---------------------------------------------------------------------------
// Repack conv weights (4*Ch, CIN, 3, 3) OIHW -> [c][ci][tap][gate] (fp32 L1 path)
// ---------------------------------------------------------------------------
__global__ __launch_bounds__(256) void repack_kernel(
    const float* __restrict__ wt, float* __restrict__ wr, int Ch, int CIN)
{
    const int n = 4 * Ch * CIN * 9;
    for (int i = blockIdx.x * 256 + threadIdx.x; i < n; i += gridDim.x * 256) {
        const int g   = i & 3;
        const int tap = (i >> 2) % 9;
        const int ci  = (i / 36) % CIN;
        const int c   = i / (36 * CIN);
        wr[i] = wt[(((size_t)(g * Ch + c)) * CIN + ci) * 9 + tap];
    }
}

// ---------------------------------------------------------------------------
// Repack conv weights into MFMA B-fragment order, fp16 hi/lo split planes.
// ---------------------------------------------------------------------------
__global__ __launch_bounds__(256) void repack_mfma_kernel(
    const float* __restrict__ wt, _Float16* __restrict__ whi, _Float16* __restrict__ wlo,
    int Ch, int CIN, int KS)
{
    const int NG = (4 * Ch) / 16;
    const int n = 9 * KS * NG * 512;
    for (int i = blockIdx.x * 256 + threadIdx.x; i < n; i += gridDim.x * 256) {
        const int j   = i & 7;
        const int l   = (i >> 3) & 63;
        const int ng  = (i >> 9) % NG;
        const int ks  = (i / (512 * NG)) % KS;
        const int tap = i / (512 * NG * KS);
        const int o   = ng * 16 + (l & 15);
        const int ci  = ks * 32 + ((l >> 4) << 3) + j;
        const float w = (ci < CIN) ? wt[((size_t)o * CIN + ci) * 9 + tap] : 0.0f;
        const _Float16 hi = (_Float16)w;
        whi[i] = hi;
        wlo[i] = (_Float16)(w - (float)hi);
    }
}

// ---------------------------------------------------------------------------
// MFMA ConvLSTM (fp16-split implicit GEMM, NHWC LDS tile, fused LSTM epilogue).
// Used for L2/L3 (numerics proven: absmax unchanged vs fp32 path, rounds 7+).
// H_T only re-tiles M across blocks; per-output MFMA k-chain is unchanged.
// ---------------------------------------------------------------------------
template<int CSPK, int Ch, int H, int W, int H_T, int KS, int CIN_S, bool POOL>
__global__ __launch_bounds__(256) void convlstm_mfma(
    const float* __restrict__ xin,
    const float* __restrict__ memin,   // (B, Ch, H, W)
    const float* __restrict__ synin,
    float* __restrict__ synout,
    float* __restrict__ memout,
    const _Float16* __restrict__ whi,
    const _Float16* __restrict__ wlo,
    const float* __restrict__ bias)    // (4*Ch)
{
    constexpr int CIN   = CSPK + Ch;
    constexpr int W2    = W + 2;
    constexpr int ROWS  = (H_T + 2) * W2;
    constexpr int NELEM = ROWS * CIN_S + 16;  // slack covers K-pad overread
    constexpr int NCG   = Ch / 16;
    constexpr int MSPLIT = H / H_T;
    constexpr int M_T   = H_T * W;
    constexpr int WM    = M_T / 4;            // px per wave
    constexpr int MF    = WM / 16;            // M-frags per wave
    constexpr int NG    = (4 * Ch) / 16;
    constexpr int SPAIRS = W / 2;
    constexpr int NCP   = CIN / 2;
    static_assert(WM % 16 == 0 && W % 16 == 0, "");
    static_assert(KS * 32 <= CIN_S + 16, "last k-read must stay inside NELEM slack");
    static_assert(CIN_S >= CIN, "channels must fit the padded stride");
    static_assert(CIN % 2 == 0 && CSPK % 2 == 0 && CIN_S % 2 == 0, "pair packing");

    __shared__ _Float16 tileH[NELEM];
    __shared__ _Float16 tileL[NELEM];

    const int tid = threadIdx.x;
    const int bid = blockIdx.x;
    const int cg = bid % NCG;
    const int ms = (bid / NCG) % MSPLIT;
    const int b  = bid / (NCG * MSPLIT);
    const int y0 = ms * H_T;
    const int c0 = cg * 16;

    {
        uint32_t* p0 = (uint32_t*)tileH;
        uint32_t* p1 = (uint32_t*)tileL;
        for (int i = tid; i < NELEM / 2; i += 256) { p0[i] = 0u; p1[i] = 0u; }
    }
    __syncthreads();

    // 2x2 packed fill: thread handles (ci, ci+1) x (x0, x0+1)
    for (int i = tid; i < NCP * (H_T + 2) * SPAIRS; i += 256) {
        const int px = i % SPAIRS;
        const int ry = (i / SPAIRS) % (H_T + 2);
        const int cp = i / (SPAIRS * (H_T + 2));
        const int ci = 2 * cp;
        const int y  = y0 + ry - 1;
        if (y < 0 || y >= H) continue;
        const int x0 = 2 * px;
        float v[2][2];   // [dci][dx]
        #pragma unroll
        for (int d = 0; d < 2; ++d) {
            const int c = ci + d;
            if (POOL && c < CSPK) {
                const float* mp = xin + (((size_t)b * CSPK + c) * (2 * H) + 2 * y) * (2 * W) + 2 * x0;
                const float4 q0 = *(const float4*)mp;
                const float4 q1 = *(const float4*)(mp + 2 * W);
                v[d][0] = ((fmaxf(fmaxf(q0.x, q0.y), fmaxf(q1.x, q1.y)) - THR) > 0.0f) ? 1.0f : 0.0f;
                v[d][1] = ((fmaxf(fmaxf(q0.z, q0.w), fmaxf(q1.z, q1.w)) - THR) > 0.0f) ? 1.0f : 0.0f;
            } else if (c < CSPK) {
                const float2 q = *(const float2*)(xin + (((size_t)b * CSPK + c) * H + y) * W + x0);
                v[d][0] = q.x; v[d][1] = q.y;
            } else {
                const float2 q = *(const float2*)(memin + (((size_t)b * Ch + (c - CSPK)) * H + y) * W + x0);
                v[d][0] = q.x; v[d][1] = q.y;
            }
        }
        #pragma unroll
        for (int dx = 0; dx < 2; ++dx) {
            const int off = (ry * W2 + x0 + dx + 1) * CIN_S + ci;   // even
            const _Float16 h0 = (_Float16)v[0][dx];
            const _Float16 h1 = (_Float16)v[1][dx];
            const _Float16 l0 = (_Float16)(v[0][dx] - (float)h0);
            const _Float16 l1 = (_Float16)(v[1][dx] - (float)h1);
            const uint32_t ph = (uint32_t)__builtin_bit_cast(uint16_t, h0)
                              | ((uint32_t)__builtin_bit_cast(uint16_t, h1) << 16);
            const uint32_t pl = (uint32_t)__builtin_bit_cast(uint16_t, l0)
                              | ((uint32_t)__builtin_bit_cast(uint16_t, l1) << 16);
            *(uint32_t*)(tileH + off) = ph;
            *(uint32_t*)(tileL + off) = pl;
        }
    }
    __syncthreads();

    const int lane = tid & 63;
    const int wid  = tid >> 6;
    const int l15  = lane & 15;
    const int lk8  = (lane >> 4) << 3;   // k offset 0/8/16/24

    f32x4 acc[MF][4];
    #pragma unroll
    for (int g = 0; g < 4; ++g) {
        const float bb = bias[g * Ch + c0 + l15];
        #pragma unroll
        for (int m = 0; m < MF; ++m) acc[m][g] = f32x4{bb, bb, bb, bb};
    }

    #pragma unroll 3
    for (int tap = 0; tap < 9; ++tap) {
        const int dy = tap / 3, dx = tap % 3;
        #pragma unroll
        for (int ks = 0; ks < KS; ++ks) {
            h8 bh[4], bl[4];
            #pragma unroll
            for (int g = 0; g < 4; ++g) {
                const size_t base = ((((size_t)tap * KS + ks) * NG + g * NCG + cg) * 64 + lane) * 8;
                bh[g] = *(const h8*)(whi + base);
                bl[g] = *(const h8*)(wlo + base);
            }
            #pragma unroll
            for (int m = 0; m < MF; ++m) {
                const int pxf = wid * WM + m * 16;
                const int yl = pxf / W;
                const int xf = pxf % W;
                const int off = ((yl + dy) * W2 + xf + l15 + dx) * CIN_S + ks * 32 + lk8;
                const h8 ah = *(const h8*)(tileH + off);
                const h8 al = *(const h8*)(tileL + off);
                #pragma unroll
                for (int g = 0; g < 4; ++g) {
                    acc[m][g] = __builtin_amdgcn_mfma_f32_16x16x32_f16(ah, bh[g], acc[m][g], 0, 0, 0);
                    acc[m][g] = __builtin_amdgcn_mfma_f32_16x16x32_f16(ah, bl[g], acc[m][g], 0, 0, 0);
                    acc[m][g] = __builtin_amdgcn_mfma_f32_16x16x32_f16(al, bh[g], acc[m][g], 0, 0, 0);
                }
            }
        }
    }

    #pragma unroll
    for (int m = 0; m < MF; ++m) {
        const int pxf = wid * WM + m * 16;
        const int yl = pxf / W;
        const int xf = pxf % W;
        const int c = c0 + l15;
        #pragma unroll
        for (int j = 0; j < 4; ++j) {
            const int x = xf + ((lane >> 4) << 2) + j;
            const size_t gaddr = (((size_t)b * Ch + c) * H + (y0 + yl)) * W + x;
            const float gi = acc[m][0][j], gf = acc[m][1][j];
            const float gg = acc[m][2][j], go = acc[m][3][j];
            const float syn = sigf(gf) * synin[gaddr] + sigf(gi) * tanh_fast(gg);
            synout[gaddr] = syn;
            memout[gaddr] = sigf(go) * tanh_fast(syn);
        }
    }
}

// ---------------------------------------------------------------------------
// fp32 ConvLSTM — L1 ONLY. DO NOT change accumulation order (ci asc, tap asc):
// L1's rounding determines a near-threshold spike; this exact order gives the
// proven absmax=0.09375 (rounds 2-7,10-12). MFMA port of L1 flipped it (r9).
// Extra block (bid == grid tail) runs fc2 of the PREVIOUS timestep with the
// EXACT wave/lane/shuffle pattern of fc2_kernel -> bitwise-identical cur5;
// it overlaps with L1's compute blocks, removing fc2 from the critical path.
// ---------------------------------------------------------------------------
template<int Cin, int Ch, int H, int W, int R, int CSPLIT, int CHUNK,
         bool POOL_IN, int MINW, int P, int NT>
__global__ __launch_bounds__(NT, MINW) void conv_lstm(
    const float* __restrict__ xin,
    const float* __restrict__ memin,
    const float* __restrict__ synin,
    float* __restrict__ synout,
    float* __restrict__ memout,
    const float* __restrict__ wr,     // repacked [c][ci][tap][gate]
    const float* __restrict__ bias,
    // fused fc2 (previous timestep); fc2_on == 0 skips (t == 0)
    const float* __restrict__ spk4_prev,
    const float* __restrict__ fc2w,
    const float* __restrict__ fc2b,
    float* __restrict__ mem5,
    float* __restrict__ out_spk,
    float* __restrict__ out_mem,
    int fc2_on)
{
    constexpr int CIN = Cin + Ch;
    constexpr int R2 = R + 2;
    constexpr int SW = W + 4;
    constexpr int ROWLANES = W / P;
    constexpr int SQ = W / 4;          // staging quads per row
    constexpr int NROUNDS = CIN / CHUNK;
    constexpr int NW = NT / 64;
    constexpr int CITERS = Ch / (CSPLIT * NW);
    constexpr int NBLK = 0;            // computed by caller; tail test below
    (void)NBLK;
    static_assert(R * ROWLANES == 64, "");
    static_assert(CIN % CHUNK == 0, "");
    static_assert(W % 4 == 0, "");

    __shared__ float tile[CHUNK * R2 * SW];

    const int tid = threadIdx.x;
    const int bid = blockIdx.x;
    const int lane = tid & 63;
    const int wid  = tid >> 6;

    // ---- fused fc2 tail block (runs previous step's fc2, wave-identical) ----
    if (bid >= CSPLIT * (H / R) * B_SZ) {
        if (fc2_on) {
            for (int task = wid; task < 2 * B_SZ; task += NW) {
                const int o = task & 1;
                const int b2 = task >> 1;
                const float* wrow = fc2w + (size_t)o * 512;
                const float* sr = spk4_prev + (size_t)b2 * 512;
                float acc2 = 0.0f;
                #pragma unroll
                for (int i = 0; i < 8; ++i)
                    acc2 = fmaf(sr[lane + i * 64], wrow[lane + i * 64], acc2);
                #pragma unroll
                for (int off = 32; off; off >>= 1) acc2 += __shfl_down(acc2, off, 64);
                if (lane == 0) {
                    const float cur = acc2 + fc2b[o];
                    const int i5 = b2 * 2 + o;
                    float m = mem5[i5];
                    const float reset = (m > THR) ? 1.0f : 0.0f;
                    m = BETA * m + cur - reset * THR;
                    out_spk[i5] = ((m - THR) > 0.0f) ? 1.0f : 0.0f;
                    out_mem[i5] = m;
                    mem5[i5] = m;
                }
            }
        }
        return;
    }

    const int cs = bid % CSPLIT;
    const int rs = (bid / CSPLIT) % (H / R);
    const int b  = bid / (CSPLIT * (H / R));
    const int r0 = rs * R;
    const int c0 = cs * (Ch / CSPLIT);

    const int ly   = lane / ROWLANES;
    const int lx   = P * (lane % ROWLANES);
    const int gy_out = r0 + ly;

    int cu[CITERS];
    #pragma unroll
    for (int k = 0; k < CITERS; ++k)
        cu[k] = __builtin_amdgcn_readfirstlane(c0 + k * NW + wid);

    float acc[CITERS][4 * P];
    #pragma unroll
    for (int k = 0; k < CITERS; ++k) {
        const float bi = bias[cu[k]];
        const float bf = bias[cu[k] + Ch];
        const float bg = bias[cu[k] + 2 * Ch];
        const float bo = bias[cu[k] + 3 * Ch];
        #pragma unroll
        for (int p = 0; p < P; ++p) {
            acc[k][0 * P + p] = bi;
            acc[k][1 * P + p] = bf;
            acc[k][2 * P + p] = bg;
            acc[k][3 * P + p] = bo;
        }
    }

    for (int rd = 0; rd < NROUNDS; ++rd) {
        const int k0 = rd * CHUNK;
        if (rd) __syncthreads();

        for (int i = tid; i < CHUNK * R2 * 4; i += NT) {
            const int col = i & 3;
            const int row = i >> 2;
            tile[row * SW + (col == 0 ? 0 : W + col)] = 0.0f;
        }
        // interior: one 4-px quad per iteration (float4 global loads)
        for (int i = tid; i < CHUNK * R2 * SQ; i += NT) {
            const int q   = i % SQ;
            const int ry  = (i / SQ) % R2;
            const int cil = i / (SQ * R2);
            const int ci  = k0 + cil;
            const int gy  = r0 + ry - 1;
            float v0 = 0.0f, v1 = 0.0f, v2 = 0.0f, v3 = 0.0f;
            if (gy >= 0 && gy < H) {
                if (POOL_IN && ci < Cin) {
                    const float* mp = xin + (((size_t)b * Cin + ci) * (2 * H) + 2 * gy) * (2 * W) + 8 * q;
                    const float4 a0 = *(const float4*)mp;
                    const float4 a1 = *(const float4*)(mp + 4);
                    const float4 b0 = *(const float4*)(mp + 2 * W);
                    const float4 b1 = *(const float4*)(mp + 2 * W + 4);
                    v0 = ((fmaxf(fmaxf(a0.x, a0.y), fmaxf(b0.x, b0.y)) - THR) > 0.0f) ? 1.0f : 0.0f;
                    v1 = ((fmaxf(fmaxf(a0.z, a0.w), fmaxf(b0.z, b0.w)) - THR) > 0.0f) ? 1.0f : 0.0f;
                    v2 = ((fmaxf(fmaxf(a1.x, a1.y), fmaxf(b1.x, b1.y)) - THR) > 0.0f) ? 1.0f : 0.0f;
                    v3 = ((fmaxf(fmaxf(a1.z, a1.w), fmaxf(b1.z, b1.w)) - THR) > 0.0f) ? 1.0f : 0.0f;
                } else if (ci < Cin) {
                    const float4 a = *(const float4*)(xin + (((size_t)b * Cin + ci) * H + gy) * W + 4 * q);
                    v0 = a.x; v1 = a.y; v2 = a.z; v3 = a.w;
                } else {
                    const float4 a = *(const float4*)(memin + (((size_t)b * Ch + (ci - Cin)) * H + gy) * W + 4 * q);
                    v0 = a.x; v1 = a.y; v2 = a.z; v3 = a.w;
                }
            }
            const int t0 = (cil * R2 + ry) * SW + 1 + 4 * q;
            tile[t0]     = v0;
            tile[t0 + 1] = v1;
            tile[t0 + 2] = v2;
            tile[t0 + 3] = v3;
        }
        __syncthreads();

        #pragma unroll 1
        for (int cil = 0; cil < CHUNK; ++cil) {
            float s[3][P + 2];
            #pragma unroll
            for (int dy = 0; dy < 3; ++dy) {
                const float* rp = &tile[(cil * R2 + ly + dy) * SW + lx];
                if constexpr (P == 4) {
                    const float4 a  = *(const float4*)rp;
                    const float2 e  = *(const float2*)(rp + 4);
                    s[dy][0] = a.x; s[dy][1] = a.y; s[dy][2] = a.z; s[dy][3] = a.w;
                    s[dy][4] = e.x; s[dy][5] = e.y;
                } else {
                    const float2 a  = *(const float2*)rp;
                    const float2 e  = *(const float2*)(rp + 2);
                    s[dy][0] = a.x; s[dy][1] = a.y; s[dy][2] = e.x; s[dy][3] = e.y;
                }
            }
            #pragma unroll
            for (int k = 0; k < CITERS; ++k) {
                const float* wp = wr + ((size_t)cu[k] * CIN + (k0 + cil)) * 36;
                #pragma unroll
                for (int tap = 0; tap < 9; ++tap) {
                    const int dy = tap / 3, dx = tap % 3;
                    const float wi  = wp[tap * 4 + 0];
                    const float wf  = wp[tap * 4 + 1];
                    const float wg_ = wp[tap * 4 + 2];
                    const float wo  = wp[tap * 4 + 3];
                    #pragma unroll
                    for (int p = 0; p < P; ++p) {
                        const float v = s[dy][p + dx];
                        acc[k][0 * P + p] = fmaf(v, wi,  acc[k][0 * P + p]);
                        acc[k][1 * P + p] = fmaf(v, wf,  acc[k][1 * P + p]);
                        acc[k][2 * P + p] = fmaf(v, wg_, acc[k][2 * P + p]);
                        acc[k][3 * P + p] = fmaf(v, wo,  acc[k][3 * P + p]);
                    }
                }
            }
        }
    }

    #pragma unroll
    for (int k = 0; k < CITERS; ++k) {
        const int c = c0 + k * NW + wid;
        const size_t base = (((size_t)b * Ch + c) * H + gy_out) * W + lx;
        float sv[P], so[P], mo[P];
        if constexpr (P == 4) {
            const float4 q = *(const float4*)(synin + base);
            sv[0] = q.x; sv[1] = q.y; sv[2] = q.z; sv[3] = q.w;
        } else {
            const float2 q = *(const float2*)(synin + base);
            sv[0] = q.x; sv[1] = q.y;
        }
        #pragma unroll
        for (int p = 0; p < P; ++p) {
            const float syn = sigf(acc[k][1 * P + p]) * sv[p]
                            + sigf(acc[k][0 * P + p]) * tanh_fast(acc[k][2 * P + p]);
            so[p] = syn;
            mo[p] = sigf(acc[k][3 * P + p]) * tanh_fast(syn);
        }
        if constexpr (P == 4) {
            *(float4*)(synout + base) = make_float4(so[0], so[1], so[2], so[3]);
            *(float4*)(memout + base) = make_float4(mo[0], mo[1], mo[2], mo[3]);
        } else {
            *(float2*)(synout + base) = make_float2(so[0], so[1]);
            *(float2*)(memout + base) = make_float2(mo[0], mo[1]);
        }
    }
}

// ---------------------------------------------------------------------------
// Fused maxpool(m3) -> spk3 -> cur4 = spk3 @ fc1_w.T + b -> Leaky(mem4).
// ---------------------------------------------------------------------------
__global__ __launch_bounds__(256) void fc1_pool_kernel(
    const float* __restrict__ m3,    // (B, 64, 4, 32)
    const float* __restrict__ wt,    // (512, 2048)
    const float* __restrict__ bias,
    float* __restrict__ mem4,
    float* __restrict__ spk4)
{
    const int wid = (blockIdx.x * 256 + threadIdx.x) >> 6;
    const int lane = threadIdx.x & 63;
    const int og = wid & 63;
    const int b = wid >> 6;
    const int o0 = og * 8;

    float acc[8] = {0, 0, 0, 0, 0, 0, 0, 0};
    for (int it = 0; it < 8; ++it) {
        const int k = (it * 64 + lane) * 4;
        const int c = k >> 5;
        const int rem = k & 31;
        const int ph = rem >> 4;
        const int pw = rem & 15;
        const float* mp = m3 + (((size_t)b * 64 + c) * 4 + 2 * ph) * 32 + 2 * pw;
        const float4 r0 = *(const float4*)mp;
        const float4 r1 = *(const float4*)(mp + 4);
        const float4 q0 = *(const float4*)(mp + 32);
        const float4 q1 = *(const float4*)(mp + 36);
        float4 sv;
        sv.x = ((fmaxf(fmaxf(r0.x, r0.y), fmaxf(q0.x, q0.y)) - THR) > 0.0f) ? 1.0f : 0.0f;
        sv.y = ((fmaxf(fmaxf(r0.z, r0.w), fmaxf(q0.z, q0.w)) - THR) > 0.0f) ? 1.0f : 0.0f;
        sv.z = ((fmaxf(fmaxf(r1.x, r1.y), fmaxf(q1.x, q1.y)) - THR) > 0.0f) ? 1.0f : 0.0f;
        sv.w = ((fmaxf(fmaxf(r1.z, r1.w), fmaxf(q1.z, q1.w)) - THR) > 0.0f) ? 1.0f : 0.0f;
        #pragma unroll
        for (int j = 0; j < 8; ++j) {
            const float4 wv = *(const float4*)(wt + (size_t)(o0 + j) * 2048 + k);
            acc[j] = fmaf(sv.x, wv.x, acc[j]);
            acc[j] = fmaf(sv.y, wv.y, acc[j]);
            acc[j] = fmaf(sv.z, wv.z, acc[j]);
            acc[j] = fmaf(sv.w, wv.w, acc[j]);
        }
    }
    float mine = 0.0f;
    #pragma unroll
    for (int j = 0; j < 8; ++j) {
        float a = acc[j];
        #pragma unroll
        for (int off = 32; off; off >>= 1) a += __shfl_xor(a, off, 64);
        if (lane == j) mine = a;
    }
    if (lane < 8) {
        const int o = o0 + lane;
        const float cur = mine + bias[o];
        const int i4 = b * 512 + o;
        float m = mem4[i4];
        const float reset = (m > THR) ? 1.0f : 0.0f;
        m = BETA * m + cur - reset * THR;
        spk4[i4] = ((m - THR) > 0.0f) ? 1.0f : 0.0f;
        mem4[i4] = m;
    }
}

// ---------------------------------------------------------------------------
// Standalone fc2 (used once, for the final timestep).
// ---------------------------------------------------------------------------
__global__ __launch_bounds__(256) void fc2_kernel(
    const float* __restrict__ spk4,
    const float* __restrict__ wt,
    const float* __restrict__ bias,
    float* __restrict__ mem5,
    float* __restrict__ out_spk,
    float* __restrict__ out_mem)
{
    const int wid = (blockIdx.x * 256 + threadIdx.x) >> 6;
    const int lane = threadIdx.x & 63;
    if (wid >= 2 * B_SZ) return;
    const int o = wid & 1;
    const int b = wid >> 1;
    const float* wr = wt + (size_t)o * 512;
    const float* sr = spk4 + (size_t)b * 512;
    float acc = 0.0f;
    #pragma unroll
    for (int i = 0; i < 8; ++i)
        acc = fmaf(sr[lane + i * 64], wr[lane + i * 64], acc);
    #pragma unroll
    for (int off = 32; off; off >>= 1) acc += __shfl_down(acc, off, 64);
    if (lane == 0) {
        const float cur = acc + bias[o];
        const int i5 = b * 2 + o;
        float m = mem5[i5];
        const float reset = (m > THR) ? 1.0f : 0.0f;
        m = BETA * m + cur - reset * THR;
        out_spk[i5] = ((m - THR) > 0.0f) ? 1.0f : 0.0f;
        out_mem[i5] = m;
        mem5[i5] = m;
    }
}

extern "C" void kernel_launch(void* const* d_in, const int* in_sizes, int n_in,
                              void* d_out, int out_size, void* d_ws, size_t ws_size,
                              hipStream_t stream) {
    (void)in_sizes; (void)n_in; (void)out_size; (void)ws_size;

    const float* x    = (const float*)d_in[0];
    const float* w1   = (const float*)d_in[1];
    const float* b1   = (const float*)d_in[2];
    const float* w2   = (const float*)d_in[3];
    const float* b2   = (const float*)d_in[4];
    const float* w3   = (const float*)d_in[5];
    const float* b3   = (const float*)d_in[6];
    const float* fc1w = (const float*)d_in[7];
    const float* fc1b = (const float*)d_in[8];
    const float* fc2w = (const float*)d_in[9];
    const float* fc2b = (const float*)d_in[10];

    float* out = (float*)d_out;
    float* ws = (float*)d_ws;

    const size_t N1 = (size_t)B_SZ * 16 * 16 * 128;
    const size_t N2 = (size_t)B_SZ * 32 * 8 * 64;
    const size_t N3 = (size_t)B_SZ * 64 * 4 * 32;

    // ---- zeroed prefix: state read before first write ----
    size_t off = 0;
    float* syn1  = ws + off; off += N1;
    float* mem1a = ws + off; off += N1;
    float* syn2  = ws + off; off += N2;
    float* mem2a = ws + off; off += N2;
    float* syn3  = ws + off; off += N3;
    float* mem3a = ws + off; off += N3;
    float* mem4  = ws + off; off += (size_t)B_SZ * 512;
    float* mem5  = ws + off; off += (size_t)B_SZ * 2;
    const size_t zero_elems = off;
    // ---- never read before written ----
    float* mem1b = ws + off; off += N1;
    float* mem2b = ws + off; off += N2;
    float* mem3b = ws + off; off += N3;
    float* spk4  = ws + off; off += (size_t)B_SZ * 512;
    float* wr1   = ws + off; off += (size_t)4 * 16 * 17 * 9;
    // fp16 fragment-ordered weight planes (offsets in floats; 2 fp16 per float)
    _Float16* whi2 = (_Float16*)(ws + off); off += 36864;   // 9*2*8*512 fp16
    _Float16* wlo2 = (_Float16*)(ws + off); off += 36864;
    _Float16* whi3 = (_Float16*)(ws + off); off += 110592;  // 9*3*16*512 fp16
    _Float16* wlo3 = (_Float16*)(ws + off); off += 110592;

    (void)hipMemsetAsync(d_ws, 0, zero_elems * sizeof(float), stream);

    repack_kernel<<<64, 256, 0, stream>>>(w1, wr1, 16, 17);
    repack_mfma_kernel<<<288, 256, 0, stream>>>(w2, whi2, wlo2, 32, 48, 2);
    repack_mfma_kernel<<<864, 256, 0, stream>>>(w3, whi3, wlo3, 64, 96, 3);

    float* m1r = mem1a; float* m1w = mem1b;
    float* m2r = mem2a; float* m2w = mem2b;
    float* m3r = mem3a; float* m3w = mem3b;

    for (int t = 0; t < T_STEPS; ++t) {
        const float* xt = x + (size_t)t * B_SZ * 16 * 128;
        const size_t oprev = (t > 0) ? (size_t)(t - 1) * 2 * B_SZ : 0;

        // L1 (fp32, numerics-pinned chain) + fused fc2(t-1) tail block.
        //   grid 512 compute blocks + 1 fc2 block; NT=512, CSPLIT=1, CHUNK=17.
        conv_lstm<1, 16, 16, 128, 2, 1, 17, false, 4, 4, 512><<<513, 512, 0, stream>>>(
            xt, m1r, syn1, syn1, m1w, wr1, b1,
            spk4, fc2w, fc2b, mem5, out + oprev, out + 3200 + oprev, t > 0 ? 1 : 0);

        // L2 (MFMA): H_T=1 -> grid 64*2*8 = 1024, LDS ~44KB, 3 blocks/CU
        convlstm_mfma<16, 32, 8, 64, 1, 2, 56, true><<<1024, 256, 0, stream>>>(
            m1w, m2r, syn2, syn2, m2w, whi2, wlo2, b2);

        // L3 (MFMA): CSPK=32, Ch=64, H=4, W=32, H_T=2, KS=3, CIN_S=104, pool
        convlstm_mfma<32, 64, 4, 32, 2, 3, 104, true><<<512, 256, 0, stream>>>(
            m2w, m3r, syn3, syn3, m3w, whi3, wlo3, b3);

        fc1_pool_kernel<<<1024, 256, 0, stream>>>(m3w, fc1w, fc1b, mem4, spk4);

        float* tmp;
        tmp = m1r; m1r = m1w; m1w = tmp;
        tmp = m2r; m2r = m2w; m2w = tmp;
        tmp = m3r; m3r = m3w; m3w = tmp;
    }

    // final timestep's fc2 (t = 24)
    const size_t olast = (size_t)(T_STEPS - 1) * 2 * B_SZ;
    fc2_kernel<<<32, 256, 0, stream>>>(
        spk4, fc2w, fc2b, mem5, out + olast, out + 3200 + olast);
}

// Round 15
// 2745.171 us; speedup vs baseline: 1.1679x; 1.1679x over previous
//
#include <hip/hip_runtime.h>
#include <math.h>
#include <stdint.h>

#define THR  0.05f
#define BETA 0.9181805491303656f
#define B_SZ 64
#define T_STEPS 25

using h8    = __attribute__((ext_vector_type(8))) _Float16;
using f32x4 = __attribute__((ext_vector_type(4))) float;

__device__ __forceinline__ float sigf(float x) { return 1.0f / (1.0f + __expf(-x)); }
__device__ __forceinline__ float tanh_fast(float x) {
    const float xc = fminf(fmaxf(x, -10.0f), 10.0f);
    const float e = __expf(2.0f * xc);
    return (e - 1.0f) / (e + 1.0f);
}

// ---------------------------------------------------------------------------
// Repack conv weights (4*Ch, CIN, 3, 3) OIHW -> [c][ci][tap][gate] (fp32 L1 path)
// ---------------------------------------------------------------------------
__global__ __launch_bounds__(256) void repack_kernel(
    const float* __restrict__ wt, float* __restrict__ wr, int Ch, int CIN)
{
    const int n = 4 * Ch * CIN * 9;
    for (int i = blockIdx.x * 256 + threadIdx.x; i < n; i += gridDim.x * 256) {
        const int g   = i & 3;
        const int tap = (i >> 2) % 9;
        const int ci  = (i / 36) % CIN;
        const int c   = i / (36 * CIN);
        wr[i] = wt[(((size_t)(g * Ch + c)) * CIN + ci) * 9 + tap];
    }
}

// ---------------------------------------------------------------------------
// Repack conv weights into MFMA B-fragment order, fp16 hi/lo split planes.
// ---------------------------------------------------------------------------
__global__ __launch_bounds__(256) void repack_mfma_kernel(
    const float* __restrict__ wt, _Float16* __restrict__ whi, _Float16* __restrict__ wlo,
    int Ch, int CIN, int KS)
{
    const int NG = (4 * Ch) / 16;
    const int n = 9 * KS * NG * 512;
    for (int i = blockIdx.x * 256 + threadIdx.x; i < n; i += gridDim.x * 256) {
        const int j   = i & 7;
        const int l   = (i >> 3) & 63;
        const int ng  = (i >> 9) % NG;
        const int ks  = (i / (512 * NG)) % KS;
        const int tap = i / (512 * NG * KS);
        const int o   = ng * 16 + (l & 15);
        const int ci  = ks * 32 + ((l >> 4) << 3) + j;
        const float w = (ci < CIN) ? wt[((size_t)o * CIN + ci) * 9 + tap] : 0.0f;
        const _Float16 hi = (_Float16)w;
        whi[i] = hi;
        wlo[i] = (_Float16)(w - (float)hi);
    }
}

// ---------------------------------------------------------------------------
// MFMA ConvLSTM (fp16-split implicit GEMM, NHWC LDS tile, fused LSTM epilogue).
// Used for L2/L3. H_T=2 is proven optimal for L2 (H_T=1 regressed: 1.5x halo
// staging + MF=1 halves B-frag amortization — round 13 lesson).
// ---------------------------------------------------------------------------
template<int CSPK, int Ch, int H, int W, int H_T, int KS, int CIN_S, bool POOL>
__global__ __launch_bounds__(256) void convlstm_mfma(
    const float* __restrict__ xin,
    const float* __restrict__ memin,   // (B, Ch, H, W)
    const float* __restrict__ synin,
    float* __restrict__ synout,
    float* __restrict__ memout,
    const _Float16* __restrict__ whi,
    const _Float16* __restrict__ wlo,
    const float* __restrict__ bias)    // (4*Ch)
{
    constexpr int CIN   = CSPK + Ch;
    constexpr int W2    = W + 2;
    constexpr int ROWS  = (H_T + 2) * W2;
    constexpr int NELEM = ROWS * CIN_S + 16;  // slack covers K-pad overread
    constexpr int NCG   = Ch / 16;
    constexpr int MSPLIT = H / H_T;
    constexpr int M_T   = H_T * W;
    constexpr int WM    = M_T / 4;            // px per wave
    constexpr int MF    = WM / 16;            // M-frags per wave
    constexpr int NG    = (4 * Ch) / 16;
    constexpr int SPAIRS = W / 2;
    constexpr int NCP   = CIN / 2;
    static_assert(WM % 16 == 0 && W % 16 == 0, "");
    static_assert(KS * 32 <= CIN_S + 16, "last k-read must stay inside NELEM slack");
    static_assert(CIN_S >= CIN, "channels must fit the padded stride");
    static_assert(CIN % 2 == 0 && CSPK % 2 == 0 && CIN_S % 2 == 0, "pair packing");

    __shared__ _Float16 tileH[NELEM];
    __shared__ _Float16 tileL[NELEM];

    const int tid = threadIdx.x;
    const int bid = blockIdx.x;
    const int cg = bid % NCG;
    const int ms = (bid / NCG) % MSPLIT;
    const int b  = bid / (NCG * MSPLIT);
    const int y0 = ms * H_T;
    const int c0 = cg * 16;

    {
        uint32_t* p0 = (uint32_t*)tileH;
        uint32_t* p1 = (uint32_t*)tileL;
        for (int i = tid; i < NELEM / 2; i += 256) { p0[i] = 0u; p1[i] = 0u; }
    }
    __syncthreads();

    // 2x2 packed fill: thread handles (ci, ci+1) x (x0, x0+1)
    for (int i = tid; i < NCP * (H_T + 2) * SPAIRS; i += 256) {
        const int px = i % SPAIRS;
        const int ry = (i / SPAIRS) % (H_T + 2);
        const int cp = i / (SPAIRS * (H_T + 2));
        const int ci = 2 * cp;
        const int y  = y0 + ry - 1;
        if (y < 0 || y >= H) continue;
        const int x0 = 2 * px;
        float v[2][2];   // [dci][dx]
        #pragma unroll
        for (int d = 0; d < 2; ++d) {
            const int c = ci + d;
            if (POOL && c < CSPK) {
                const float* mp = xin + (((size_t)b * CSPK + c) * (2 * H) + 2 * y) * (2 * W) + 2 * x0;
                const float4 q0 = *(const float4*)mp;
                const float4 q1 = *(const float4*)(mp + 2 * W);
                v[d][0] = ((fmaxf(fmaxf(q0.x, q0.y), fmaxf(q1.x, q1.y)) - THR) > 0.0f) ? 1.0f : 0.0f;
                v[d][1] = ((fmaxf(fmaxf(q0.z, q0.w), fmaxf(q1.z, q1.w)) - THR) > 0.0f) ? 1.0f : 0.0f;
            } else if (c < CSPK) {
                const float2 q = *(const float2*)(xin + (((size_t)b * CSPK + c) * H + y) * W + x0);
                v[d][0] = q.x; v[d][1] = q.y;
            } else {
                const float2 q = *(const float2*)(memin + (((size_t)b * Ch + (c - CSPK)) * H + y) * W + x0);
                v[d][0] = q.x; v[d][1] = q.y;
            }
        }
        #pragma unroll
        for (int dx = 0; dx < 2; ++dx) {
            const int off = (ry * W2 + x0 + dx + 1) * CIN_S + ci;   // even
            const _Float16 h0 = (_Float16)v[0][dx];
            const _Float16 h1 = (_Float16)v[1][dx];
            const _Float16 l0 = (_Float16)(v[0][dx] - (float)h0);
            const _Float16 l1 = (_Float16)(v[1][dx] - (float)h1);
            const uint32_t ph = (uint32_t)__builtin_bit_cast(uint16_t, h0)
                              | ((uint32_t)__builtin_bit_cast(uint16_t, h1) << 16);
            const uint32_t pl = (uint32_t)__builtin_bit_cast(uint16_t, l0)
                              | ((uint32_t)__builtin_bit_cast(uint16_t, l1) << 16);
            *(uint32_t*)(tileH + off) = ph;
            *(uint32_t*)(tileL + off) = pl;
        }
    }
    __syncthreads();

    const int lane = tid & 63;
    const int wid  = tid >> 6;
    const int l15  = lane & 15;
    const int lk8  = (lane >> 4) << 3;   // k offset 0/8/16/24

    f32x4 acc[MF][4];
    #pragma unroll
    for (int g = 0; g < 4; ++g) {
        const float bb = bias[g * Ch + c0 + l15];
        #pragma unroll
        for (int m = 0; m < MF; ++m) acc[m][g] = f32x4{bb, bb, bb, bb};
    }

    #pragma unroll 3
    for (int tap = 0; tap < 9; ++tap) {
        const int dy = tap / 3, dx = tap % 3;
        #pragma unroll
        for (int ks = 0; ks < KS; ++ks) {
            h8 bh[4], bl[4];
            #pragma unroll
            for (int g = 0; g < 4; ++g) {
                const size_t base = ((((size_t)tap * KS + ks) * NG + g * NCG + cg) * 64 + lane) * 8;
                bh[g] = *(const h8*)(whi + base);
                bl[g] = *(const h8*)(wlo + base);
            }
            #pragma unroll
            for (int m = 0; m < MF; ++m) {
                const int pxf = wid * WM + m * 16;
                const int yl = pxf / W;
                const int xf = pxf % W;
                const int off = ((yl + dy) * W2 + xf + l15 + dx) * CIN_S + ks * 32 + lk8;
                const h8 ah = *(const h8*)(tileH + off);
                const h8 al = *(const h8*)(tileL + off);
                #pragma unroll
                for (int g = 0; g < 4; ++g) {
                    acc[m][g] = __builtin_amdgcn_mfma_f32_16x16x32_f16(ah, bh[g], acc[m][g], 0, 0, 0);
                    acc[m][g] = __builtin_amdgcn_mfma_f32_16x16x32_f16(ah, bl[g], acc[m][g], 0, 0, 0);
                    acc[m][g] = __builtin_amdgcn_mfma_f32_16x16x32_f16(al, bh[g], acc[m][g], 0, 0, 0);
                }
            }
        }
    }

    #pragma unroll
    for (int m = 0; m < MF; ++m) {
        const int pxf = wid * WM + m * 16;
        const int yl = pxf / W;
        const int xf = pxf % W;
        const int c = c0 + l15;
        #pragma unroll
        for (int j = 0; j < 4; ++j) {
            const int x = xf + ((lane >> 4) << 2) + j;
            const size_t gaddr = (((size_t)b * Ch + c) * H + (y0 + yl)) * W + x;
            const float gi = acc[m][0][j], gf = acc[m][1][j];
            const float gg = acc[m][2][j], go = acc[m][3][j];
            const float syn = sigf(gf) * synin[gaddr] + sigf(gi) * tanh_fast(gg);
            synout[gaddr] = syn;
            memout[gaddr] = sigf(go) * tanh_fast(syn);
        }
    }
}

// ---------------------------------------------------------------------------
// fp32 ConvLSTM — L1 ONLY. DO NOT change accumulation order (ci asc, tap asc):
// L1's rounding determines a near-threshold spike; this exact order gives the
// proven absmax=0.09375 (rounds 2-7,10-13). MFMA port of L1 flipped it (r9).
// Tail block runs fc2 of the PREVIOUS timestep (wave-identical to fc2_kernel
// -> bitwise-same cur5), overlapping with L1 compute — proven −450 µs (r13).
// ---------------------------------------------------------------------------
template<int Cin, int Ch, int H, int W, int R, int CSPLIT, int CHUNK,
         bool POOL_IN, int MINW, int P, int NT>
__global__ __launch_bounds__(NT, MINW) void conv_lstm(
    const float* __restrict__ xin,
    const float* __restrict__ memin,
    const float* __restrict__ synin,
    float* __restrict__ synout,
    float* __restrict__ memout,
    const float* __restrict__ wr,     // repacked [c][ci][tap][gate]
    const float* __restrict__ bias,
    // fused fc2 (previous timestep); fc2_on == 0 skips (t == 0)
    const float* __restrict__ spk4_prev,
    const float* __restrict__ fc2w,
    const float* __restrict__ fc2b,
    float* __restrict__ mem5,
    float* __restrict__ out_spk,
    float* __restrict__ out_mem,
    int fc2_on)
{
    constexpr int CIN = Cin + Ch;
    constexpr int R2 = R + 2;
    constexpr int SW = W + 4;
    constexpr int ROWLANES = W / P;
    constexpr int SQ = W / 4;          // staging quads per row
    constexpr int NROUNDS = CIN / CHUNK;
    constexpr int NW = NT / 64;
    constexpr int CITERS = Ch / (CSPLIT * NW);
    static_assert(R * ROWLANES == 64, "");
    static_assert(CIN % CHUNK == 0, "");
    static_assert(W % 4 == 0, "");

    __shared__ float tile[CHUNK * R2 * SW];

    const int tid = threadIdx.x;
    const int bid = blockIdx.x;
    const int lane = tid & 63;
    const int wid  = tid >> 6;

    // ---- fused fc2 tail block (runs previous step's fc2, wave-identical) ----
    if (bid >= CSPLIT * (H / R) * B_SZ) {
        if (fc2_on) {
            for (int task = wid; task < 2 * B_SZ; task += NW) {
                const int o = task & 1;
                const int b2 = task >> 1;
                const float* wrow = fc2w + (size_t)o * 512;
                const float* sr = spk4_prev + (size_t)b2 * 512;
                float acc2 = 0.0f;
                #pragma unroll
                for (int i = 0; i < 8; ++i)
                    acc2 = fmaf(sr[lane + i * 64], wrow[lane + i * 64], acc2);
                #pragma unroll
                for (int off = 32; off; off >>= 1) acc2 += __shfl_down(acc2, off, 64);
                if (lane == 0) {
                    const float cur = acc2 + fc2b[o];
                    const int i5 = b2 * 2 + o;
                    float m = mem5[i5];
                    const float reset = (m > THR) ? 1.0f : 0.0f;
                    m = BETA * m + cur - reset * THR;
                    out_spk[i5] = ((m - THR) > 0.0f) ? 1.0f : 0.0f;
                    out_mem[i5] = m;
                    mem5[i5] = m;
                }
            }
        }
        return;
    }

    const int cs = bid % CSPLIT;
    const int rs = (bid / CSPLIT) % (H / R);
    const int b  = bid / (CSPLIT * (H / R));
    const int r0 = rs * R;
    const int c0 = cs * (Ch / CSPLIT);

    const int ly   = lane / ROWLANES;
    const int lx   = P * (lane % ROWLANES);
    const int gy_out = r0 + ly;

    int cu[CITERS];
    #pragma unroll
    for (int k = 0; k < CITERS; ++k)
        cu[k] = __builtin_amdgcn_readfirstlane(c0 + k * NW + wid);

    float acc[CITERS][4 * P];
    #pragma unroll
    for (int k = 0; k < CITERS; ++k) {
        const float bi = bias[cu[k]];
        const float bf = bias[cu[k] + Ch];
        const float bg = bias[cu[k] + 2 * Ch];
        const float bo = bias[cu[k] + 3 * Ch];
        #pragma unroll
        for (int p = 0; p < P; ++p) {
            acc[k][0 * P + p] = bi;
            acc[k][1 * P + p] = bf;
            acc[k][2 * P + p] = bg;
            acc[k][3 * P + p] = bo;
        }
    }

    for (int rd = 0; rd < NROUNDS; ++rd) {
        const int k0 = rd * CHUNK;
        if (rd) __syncthreads();

        for (int i = tid; i < CHUNK * R2 * 4; i += NT) {
            const int col = i & 3;
            const int row = i >> 2;
            tile[row * SW + (col == 0 ? 0 : W + col)] = 0.0f;
        }
        // interior: one 4-px quad per iteration (float4 global loads)
        for (int i = tid; i < CHUNK * R2 * SQ; i += NT) {
            const int q   = i % SQ;
            const int ry  = (i / SQ) % R2;
            const int cil = i / (SQ * R2);
            const int ci  = k0 + cil;
            const int gy  = r0 + ry - 1;
            float v0 = 0.0f, v1 = 0.0f, v2 = 0.0f, v3 = 0.0f;
            if (gy >= 0 && gy < H) {
                if (POOL_IN && ci < Cin) {
                    const float* mp = xin + (((size_t)b * Cin + ci) * (2 * H) + 2 * gy) * (2 * W) + 8 * q;
                    const float4 a0 = *(const float4*)mp;
                    const float4 a1 = *(const float4*)(mp + 4);
                    const float4 b0 = *(const float4*)(mp + 2 * W);
                    const float4 b1 = *(const float4*)(mp + 2 * W + 4);
                    v0 = ((fmaxf(fmaxf(a0.x, a0.y), fmaxf(b0.x, b0.y)) - THR) > 0.0f) ? 1.0f : 0.0f;
                    v1 = ((fmaxf(fmaxf(a0.z, a0.w), fmaxf(b0.z, b0.w)) - THR) > 0.0f) ? 1.0f : 0.0f;
                    v2 = ((fmaxf(fmaxf(a1.x, a1.y), fmaxf(b1.x, b1.y)) - THR) > 0.0f) ? 1.0f : 0.0f;
                    v3 = ((fmaxf(fmaxf(a1.z, a1.w), fmaxf(b1.z, b1.w)) - THR) > 0.0f) ? 1.0f : 0.0f;
                } else if (ci < Cin) {
                    const float4 a = *(const float4*)(xin + (((size_t)b * Cin + ci) * H + gy) * W + 4 * q);
                    v0 = a.x; v1 = a.y; v2 = a.z; v3 = a.w;
                } else {
                    const float4 a = *(const float4*)(memin + (((size_t)b * Ch + (ci - Cin)) * H + gy) * W + 4 * q);
                    v0 = a.x; v1 = a.y; v2 = a.z; v3 = a.w;
                }
            }
            const int t0 = (cil * R2 + ry) * SW + 1 + 4 * q;
            tile[t0]     = v0;
            tile[t0 + 1] = v1;
            tile[t0 + 2] = v2;
            tile[t0 + 3] = v3;
        }
        __syncthreads();

        #pragma unroll 1
        for (int cil = 0; cil < CHUNK; ++cil) {
            float s[3][P + 2];
            #pragma unroll
            for (int dy = 0; dy < 3; ++dy) {
                const float* rp = &tile[(cil * R2 + ly + dy) * SW + lx];
                if constexpr (P == 4) {
                    const float4 a  = *(const float4*)rp;
                    const float2 e  = *(const float2*)(rp + 4);
                    s[dy][0] = a.x; s[dy][1] = a.y; s[dy][2] = a.z; s[dy][3] = a.w;
                    s[dy][4] = e.x; s[dy][5] = e.y;
                } else {
                    const float2 a  = *(const float2*)rp;
                    const float2 e  = *(const float2*)(rp + 2);
                    s[dy][0] = a.x; s[dy][1] = a.y; s[dy][2] = e.x; s[dy][3] = e.y;
                }
            }
            #pragma unroll
            for (int k = 0; k < CITERS; ++k) {
                const float* wp = wr + ((size_t)cu[k] * CIN + (k0 + cil)) * 36;
                #pragma unroll
                for (int tap = 0; tap < 9; ++tap) {
                    const int dy = tap / 3, dx = tap % 3;
                    const float wi  = wp[tap * 4 + 0];
                    const float wf  = wp[tap * 4 + 1];
                    const float wg_ = wp[tap * 4 + 2];
                    const float wo  = wp[tap * 4 + 3];
                    #pragma unroll
                    for (int p = 0; p < P; ++p) {
                        const float v = s[dy][p + dx];
                        acc[k][0 * P + p] = fmaf(v, wi,  acc[k][0 * P + p]);
                        acc[k][1 * P + p] = fmaf(v, wf,  acc[k][1 * P + p]);
                        acc[k][2 * P + p] = fmaf(v, wg_, acc[k][2 * P + p]);
                        acc[k][3 * P + p] = fmaf(v, wo,  acc[k][3 * P + p]);
                    }
                }
            }
        }
    }

    #pragma unroll
    for (int k = 0; k < CITERS; ++k) {
        const int c = c0 + k * NW + wid;
        const size_t base = (((size_t)b * Ch + c) * H + gy_out) * W + lx;
        float sv[P], so[P], mo[P];
        if constexpr (P == 4) {
            const float4 q = *(const float4*)(synin + base);
            sv[0] = q.x; sv[1] = q.y; sv[2] = q.z; sv[3] = q.w;
        } else {
            const float2 q = *(const float2*)(synin + base);
            sv[0] = q.x; sv[1] = q.y;
        }
        #pragma unroll
        for (int p = 0; p < P; ++p) {
            const float syn = sigf(acc[k][1 * P + p]) * sv[p]
                            + sigf(acc[k][0 * P + p]) * tanh_fast(acc[k][2 * P + p]);
            so[p] = syn;
            mo[p] = sigf(acc[k][3 * P + p]) * tanh_fast(syn);
        }
        if constexpr (P == 4) {
            *(float4*)(synout + base) = make_float4(so[0], so[1], so[2], so[3]);
            *(float4*)(memout + base) = make_float4(mo[0], mo[1], mo[2], mo[3]);
        } else {
            *(float2*)(synout + base) = make_float2(so[0], so[1]);
            *(float2*)(memout + base) = make_float2(mo[0], mo[1]);
        }
    }
}

// ---------------------------------------------------------------------------
// Fused maxpool(m3) -> spk3 -> cur4 = spk3 @ fc1_w.T + b -> Leaky(mem4).
// ---------------------------------------------------------------------------
__global__ __launch_bounds__(256) void fc1_pool_kernel(
    const float* __restrict__ m3,    // (B, 64, 4, 32)
    const float* __restrict__ wt,    // (512, 2048)
    const float* __restrict__ bias,
    float* __restrict__ mem4,
    float* __restrict__ spk4)
{
    const int wid = (blockIdx.x * 256 + threadIdx.x) >> 6;
    const int lane = threadIdx.x & 63;
    const int og = wid & 63;
    const int b = wid >> 6;
    const int o0 = og * 8;

    float acc[8] = {0, 0, 0, 0, 0, 0, 0, 0};
    for (int it = 0; it < 8; ++it) {
        const int k = (it * 64 + lane) * 4;
        const int c = k >> 5;
        const int rem = k & 31;
        const int ph = rem >> 4;
        const int pw = rem & 15;
        const float* mp = m3 + (((size_t)b * 64 + c) * 4 + 2 * ph) * 32 + 2 * pw;
        const float4 r0 = *(const float4*)mp;
        const float4 r1 = *(const float4*)(mp + 4);
        const float4 q0 = *(const float4*)(mp + 32);
        const float4 q1 = *(const float4*)(mp + 36);
        float4 sv;
        sv.x = ((fmaxf(fmaxf(r0.x, r0.y), fmaxf(q0.x, q0.y)) - THR) > 0.0f) ? 1.0f : 0.0f;
        sv.y = ((fmaxf(fmaxf(r0.z, r0.w), fmaxf(q0.z, q0.w)) - THR) > 0.0f) ? 1.0f : 0.0f;
        sv.z = ((fmaxf(fmaxf(r1.x, r1.y), fmaxf(q1.x, q1.y)) - THR) > 0.0f) ? 1.0f : 0.0f;
        sv.w = ((fmaxf(fmaxf(r1.z, r1.w), fmaxf(q1.z, q1.w)) - THR) > 0.0f) ? 1.0f : 0.0f;
        #pragma unroll
        for (int j = 0; j < 8; ++j) {
            const float4 wv = *(const float4*)(wt + (size_t)(o0 + j) * 2048 + k);
            acc[j] = fmaf(sv.x, wv.x, acc[j]);
            acc[j] = fmaf(sv.y, wv.y, acc[j]);
            acc[j] = fmaf(sv.z, wv.z, acc[j]);
            acc[j] = fmaf(sv.w, wv.w, acc[j]);
        }
    }
    float mine = 0.0f;
    #pragma unroll
    for (int j = 0; j < 8; ++j) {
        float a = acc[j];
        #pragma unroll
        for (int off = 32; off; off >>= 1) a += __shfl_xor(a, off, 64);
        if (lane == j) mine = a;
    }
    if (lane < 8) {
        const int o = o0 + lane;
        const float cur = mine + bias[o];
        const int i4 = b * 512 + o;
        float m = mem4[i4];
        const float reset = (m > THR) ? 1.0f : 0.0f;
        m = BETA * m + cur - reset * THR;
        spk4[i4] = ((m - THR) > 0.0f) ? 1.0f : 0.0f;
        mem4[i4] = m;
    }
}

// ---------------------------------------------------------------------------
// Standalone fc2 (used once, for the final timestep).
// ---------------------------------------------------------------------------
__global__ __launch_bounds__(256) void fc2_kernel(
    const float* __restrict__ spk4,
    const float* __restrict__ wt,
    const float* __restrict__ bias,
    float* __restrict__ mem5,
    float* __restrict__ out_spk,
    float* __restrict__ out_mem)
{
    const int wid = (blockIdx.x * 256 + threadIdx.x) >> 6;
    const int lane = threadIdx.x & 63;
    if (wid >= 2 * B_SZ) return;
    const int o = wid & 1;
    const int b = wid >> 1;
    const float* wr = wt + (size_t)o * 512;
    const float* sr = spk4 + (size_t)b * 512;
    float acc = 0.0f;
    #pragma unroll
    for (int i = 0; i < 8; ++i)
        acc = fmaf(sr[lane + i * 64], wr[lane + i * 64], acc);
    #pragma unroll
    for (int off = 32; off; off >>= 1) acc += __shfl_down(acc, off, 64);
    if (lane == 0) {
        const float cur = acc + bias[o];
        const int i5 = b * 2 + o;
        float m = mem5[i5];
        const float reset = (m > THR) ? 1.0f : 0.0f;
        m = BETA * m + cur - reset * THR;
        out_spk[i5] = ((m - THR) > 0.0f) ? 1.0f : 0.0f;
        out_mem[i5] = m;
        mem5[i5] = m;
    }
}

extern "C" void kernel_launch(void* const* d_in, const int* in_sizes, int n_in,
                              void* d_out, int out_size, void* d_ws, size_t ws_size,
                              hipStream_t stream) {
    (void)in_sizes; (void)n_in; (void)out_size; (void)ws_size;

    const float* x    = (const float*)d_in[0];
    const float* w1   = (const float*)d_in[1];
    const float* b1   = (const float*)d_in[2];
    const float* w2   = (const float*)d_in[3];
    const float* b2   = (const float*)d_in[4];
    const float* w3   = (const float*)d_in[5];
    const float* b3   = (const float*)d_in[6];
    const float* fc1w = (const float*)d_in[7];
    const float* fc1b = (const float*)d_in[8];
    const float* fc2w = (const float*)d_in[9];
    const float* fc2b = (const float*)d_in[10];

    float* out = (float*)d_out;
    float* ws = (float*)d_ws;

    const size_t N1 = (size_t)B_SZ * 16 * 16 * 128;
    const size_t N2 = (size_t)B_SZ * 32 * 8 * 64;
    const size_t N3 = (size_t)B_SZ * 64 * 4 * 32;

    // ---- zeroed prefix: state read before first write ----
    size_t off = 0;
    float* syn1  = ws + off; off += N1;
    float* mem1a = ws + off; off += N1;
    float* syn2  = ws + off; off += N2;
    float* mem2a = ws + off; off += N2;
    float* syn3  = ws + off; off += N3;
    float* mem3a = ws + off; off += N3;
    float* mem4  = ws + off; off += (size_t)B_SZ * 512;
    float* mem5  = ws + off; off += (size_t)B_SZ * 2;
    const size_t zero_elems = off;
    // ---- never read before written ----
    float* mem1b = ws + off; off += N1;
    float* mem2b = ws + off; off += N2;
    float* mem3b = ws + off; off += N3;
    float* spk4  = ws + off; off += (size_t)B_SZ * 512;
    float* wr1   = ws + off; off += (size_t)4 * 16 * 17 * 9;
    // fp16 fragment-ordered weight planes (offsets in floats; 2 fp16 per float)
    _Float16* whi2 = (_Float16*)(ws + off); off += 36864;   // 9*2*8*512 fp16
    _Float16* wlo2 = (_Float16*)(ws + off); off += 36864;
    _Float16* whi3 = (_Float16*)(ws + off); off += 110592;  // 9*3*16*512 fp16
    _Float16* wlo3 = (_Float16*)(ws + off); off += 110592;

    (void)hipMemsetAsync(d_ws, 0, zero_elems * sizeof(float), stream);

    repack_kernel<<<64, 256, 0, stream>>>(w1, wr1, 16, 17);
    repack_mfma_kernel<<<288, 256, 0, stream>>>(w2, whi2, wlo2, 32, 48, 2);
    repack_mfma_kernel<<<864, 256, 0, stream>>>(w3, whi3, wlo3, 64, 96, 3);

    float* m1r = mem1a; float* m1w = mem1b;
    float* m2r = mem2a; float* m2w = mem2b;
    float* m3r = mem3a; float* m3w = mem3b;

    for (int t = 0; t < T_STEPS; ++t) {
        const float* xt = x + (size_t)t * B_SZ * 16 * 128;
        const size_t oprev = (t > 0) ? (size_t)(t - 1) * 2 * B_SZ : 0;

        // L1 (fp32, numerics-pinned chain) + fused fc2(t-1) tail block.
        //   grid 512 compute blocks + 1 fc2 block; NT=512, CSPLIT=1, CHUNK=17.
        conv_lstm<1, 16, 16, 128, 2, 1, 17, false, 4, 4, 512><<<513, 512, 0, stream>>>(
            xt, m1r, syn1, syn1, m1w, wr1, b1,
            spk4, fc2w, fc2b, mem5, out + oprev, out + 3200 + oprev, t > 0 ? 1 : 0);

        // L2 (MFMA): H_T=2 (proven; H_T=1 regressed r13) -> grid 512, LDS ~58KB
        convlstm_mfma<16, 32, 8, 64, 2, 2, 56, true><<<512, 256, 0, stream>>>(
            m1w, m2r, syn2, syn2, m2w, whi2, wlo2, b2);

        // L3 (MFMA): CSPK=32, Ch=64, H=4, W=32, H_T=2, KS=3, CIN_S=104, pool
        convlstm_mfma<32, 64, 4, 32, 2, 3, 104, true><<<512, 256, 0, stream>>>(
            m2w, m3r, syn3, syn3, m3w, whi3, wlo3, b3);

        fc1_pool_kernel<<<1024, 256, 0, stream>>>(m3w, fc1w, fc1b, mem4, spk4);

        float* tmp;
        tmp = m1r; m1r = m1w; m1w = tmp;
        tmp = m2r; m2r = m2w; m2w = tmp;
        tmp = m3r; m3r = m3w; m3w = tmp;
    }

    // final timestep's fc2 (t = 24)
    const size_t olast = (size_t)(T_STEPS - 1) * 2 * B_SZ;
    fc2_kernel<<<32, 256, 0, stream>>>(
        spk4, fc2w, fc2b, mem5, out + olast, out + 3200 + olast);
}